// Round 2
// baseline (475.216 us; speedup 1.0000x reference)
//
#include <hip/hip_runtime.h>
#include <math.h>

#define F_DIM 64
#define K_CL 16
#define B_GR 16

// ---------------------------------------------------------------------------
// K1: s = x@W + b ; ss = softmax(s). One thread per node. fp32 in/out.
// ---------------------------------------------------------------------------
__global__ __launch_bounds__(256) void k_assign(
    const float* __restrict__ x, const float* __restrict__ W, const float* __restrict__ bvec,
    float* __restrict__ ss, float* __restrict__ sraw)
{
    __shared__ float Wl[F_DIM * K_CL];
    __shared__ float bl[K_CL];
    int t = threadIdx.x;
    for (int idx = t; idx < F_DIM * K_CL; idx += 256) Wl[idx] = W[idx];
    if (t < K_CL) bl[t] = bvec[t];
    __syncthreads();

    size_t i = (size_t)blockIdx.x * 256 + t;
    float s[K_CL];
#pragma unroll
    for (int k = 0; k < 16; ++k) s[k] = bl[k];

    const float4* xp = reinterpret_cast<const float4*>(x + i * F_DIM);
#pragma unroll
    for (int j = 0; j < 16; ++j) {
        float4 q = xp[j];
        float xf[4] = {q.x, q.y, q.z, q.w};
#pragma unroll
        for (int ff = 0; ff < 4; ++ff) {
            int f = j * 4 + ff;
            float xv = xf[ff];
            const float4* wr = reinterpret_cast<const float4*>(&Wl[f * K_CL]);
            float4 w0 = wr[0], w1 = wr[1], w2 = wr[2], w3 = wr[3];
            s[0]  += xv * w0.x; s[1]  += xv * w0.y; s[2]  += xv * w0.z; s[3]  += xv * w0.w;
            s[4]  += xv * w1.x; s[5]  += xv * w1.y; s[6]  += xv * w1.z; s[7]  += xv * w1.w;
            s[8]  += xv * w2.x; s[9]  += xv * w2.y; s[10] += xv * w2.z; s[11] += xv * w2.w;
            s[12] += xv * w3.x; s[13] += xv * w3.y; s[14] += xv * w3.z; s[15] += xv * w3.w;
        }
    }

    float4* sp = reinterpret_cast<float4*>(sraw + i * K_CL);
    sp[0] = make_float4(s[0], s[1], s[2], s[3]);
    sp[1] = make_float4(s[4], s[5], s[6], s[7]);
    sp[2] = make_float4(s[8], s[9], s[10], s[11]);
    sp[3] = make_float4(s[12], s[13], s[14], s[15]);

    float m = s[0];
#pragma unroll
    for (int k = 1; k < 16; ++k) m = fmaxf(m, s[k]);
    float sum = 0.f;
#pragma unroll
    for (int k = 0; k < 16; ++k) { s[k] = __expf(s[k] - m); sum += s[k]; }
    float inv = 1.0f / sum;
    float4* qp = reinterpret_cast<float4*>(ss + i * K_CL);
    qp[0] = make_float4(s[0] * inv, s[1] * inv, s[2] * inv, s[3] * inv);
    qp[1] = make_float4(s[4] * inv, s[5] * inv, s[6] * inv, s[7] * inv);
    qp[2] = make_float4(s[8] * inv, s[9] * inv, s[10] * inv, s[11] * inv);
    qp[3] = make_float4(s[12] * inv, s[13] * inv, s[14] * inv, s[15] * inv);
}

// ---------------------------------------------------------------------------
// K2: out_adj[b,k,l] += w * ss[row,k] * ss[col,l]  (per-edge rank-1),
//     fused degree d[col] += w. 16-lane groups, lane = k, acc over l.
// ---------------------------------------------------------------------------
__global__ __launch_bounds__(256) void k_edge(
    const int* __restrict__ erow, const int* __restrict__ ecol, const float* __restrict__ ew,
    const float* __restrict__ ss, float* __restrict__ oadj, float* __restrict__ dvec,
    int epg, int edges_per_graph, int nmask)
{
    __shared__ float CCl[K_CL * K_CL];
    int t = threadIdx.x;
    CCl[t] = 0.f;
    __syncthreads();

    int grp = t >> 4;
    int k = t & 15;
    size_t base = ((size_t)blockIdx.x * 16 + grp) * epg;

    float acc[16];
#pragma unroll
    for (int l = 0; l < 16; ++l) acc[l] = 0.f;

#pragma unroll 2
    for (int j = 0; j < epg; ++j) {
        size_t e = base + j;
        int r = erow[e] & nmask;
        int c = ecol[e] & nmask;
        float w = ew[e];
        float a = ss[(size_t)r * 16 + k] * w;
        const float4* bp = reinterpret_cast<const float4*>(ss + (size_t)c * 16);
        float4 b0 = bp[0], b1 = bp[1], b2 = bp[2], b3 = bp[3];
        acc[0]  += a * b0.x; acc[1]  += a * b0.y; acc[2]  += a * b0.z; acc[3]  += a * b0.w;
        acc[4]  += a * b1.x; acc[5]  += a * b1.y; acc[6]  += a * b1.z; acc[7]  += a * b1.w;
        acc[8]  += a * b2.x; acc[9]  += a * b2.y; acc[10] += a * b2.z; acc[11] += a * b2.w;
        acc[12] += a * b3.x; acc[13] += a * b3.y; acc[14] += a * b3.z; acc[15] += a * b3.w;
        if (k == 0) atomicAdd(dvec + c, w);
    }

#pragma unroll
    for (int l = 0; l < 16; ++l) atomicAdd(&CCl[k * 16 + l], acc[l]);
    __syncthreads();

    int graph = (int)(((size_t)blockIdx.x * 16 * epg) / (size_t)edges_per_graph);
    atomicAdd(oadj + graph * 256 + t, CCl[t]);
}

// ---------------------------------------------------------------------------
// K3: out_x_acc[g,k,f] = sum_i s[i,k] * x[i,f].  lane = f (64), acc[16] over k.
// ---------------------------------------------------------------------------
__global__ __launch_bounds__(256) void k_outx(
    const float* __restrict__ x, const float* __restrict__ sraw,
    float* __restrict__ outx_acc, int npw, int npg)
{
    int t = threadIdx.x;
    int wid = t >> 6, lane = t & 63;
    size_t base = ((size_t)blockIdx.x * 4 + wid) * npw;

    float acc[16];
#pragma unroll
    for (int k = 0; k < 16; ++k) acc[k] = 0.f;

    for (int j = 0; j < npw; ++j) {
        size_t i = base + j;
        float xv = x[i * F_DIM + lane];
        const float4* sp = reinterpret_cast<const float4*>(sraw + i * K_CL);
        float4 s0 = sp[0], s1 = sp[1], s2 = sp[2], s3 = sp[3];
        acc[0]  += s0.x * xv; acc[1]  += s0.y * xv; acc[2]  += s0.z * xv; acc[3]  += s0.w * xv;
        acc[4]  += s1.x * xv; acc[5]  += s1.y * xv; acc[6]  += s1.z * xv; acc[7]  += s1.w * xv;
        acc[8]  += s2.x * xv; acc[9]  += s2.y * xv; acc[10] += s2.z * xv; acc[11] += s2.w * xv;
        acc[12] += s3.x * xv; acc[13] += s3.y * xv; acc[14] += s3.z * xv; acc[15] += s3.w * xv;
    }
    int g = (int)(base / (size_t)npg);
    float* dst = outx_acc + g * (K_CL * F_DIM) + lane;
#pragma unroll
    for (int k = 0; k < 16; ++k) atomicAdd(dst + k * F_DIM, acc[k]);
}

// ---------------------------------------------------------------------------
// K4: CC = ss^T ss per graph, dS = d^T ss, cluster_size, m2.
// ---------------------------------------------------------------------------
__global__ __launch_bounds__(256) void k_node(
    const float* __restrict__ ss, const float* __restrict__ dvec,
    float* __restrict__ CCb, float* __restrict__ dSb, float* __restrict__ csb,
    float* __restrict__ m2b, int npw, int npg)
{
    int t = threadIdx.x;
    int wid = t >> 6, lane = t & 63;
    int g4 = lane >> 4, l = lane & 15;
    size_t base = ((size_t)blockIdx.x * 4 + wid) * npw;

    float acc[4] = {0.f, 0.f, 0.f, 0.f};
    float accds = 0.f, acccs = 0.f, accm2 = 0.f;

    for (int j = 0; j < npw; ++j) {
        size_t i = base + j;
        float sv = ss[i * K_CL + l];
        float di = dvec[i];
#pragma unroll
        for (int j4 = 0; j4 < 4; ++j4) {
            int k = g4 * 4 + j4;
            float ak = __shfl(sv, k, 16);
            acc[j4] += ak * sv;
        }
        accds += di * sv;
        acccs += sv;
        accm2 += di;
    }
    int g = (int)(base / (size_t)npg);
#pragma unroll
    for (int j4 = 0; j4 < 4; ++j4)
        atomicAdd(CCb + g * 256 + (g4 * 4 + j4) * 16 + l, acc[j4]);
    if (g4 == 0) {
        atomicAdd(dSb + g * 16 + l, accds);
        atomicAdd(csb + g * 16 + l, acccs);
    }
    if (lane == 0) atomicAdd(m2b + g, accm2);
}

// ---------------------------------------------------------------------------
// K5: finalize — selu(out_x), losses, out_adj_norm. One block, thread=(b,k).
// ---------------------------------------------------------------------------
__global__ __launch_bounds__(256) void k_final(
    const float* __restrict__ outx_acc, const float* __restrict__ oadj,
    const float* __restrict__ CCb, const float* __restrict__ dSb,
    const float* __restrict__ csb, const float* __restrict__ m2b,
    float* __restrict__ out, int npg)
{
    int t = threadIdx.x;

    // selu(out_x) -> out[0 .. 16383]
    for (int idx = t; idx < B_GR * K_CL * F_DIM; idx += 256) {
        float v = outx_acc[idx];
        float r = (v > 0.f) ? (1.0507009873554805f * v)
                            : (1.0507009873554805f * 1.6732632423543772f * (__expf(v) - 1.0f));
        out[idx] = r;
    }

    int b = t >> 4, k = t & 15;
    const float* oar = oadj + b * 256 + k * 16;
    const float* ccr = CCb + b * 256 + k * 16;

    float rowsum = 0.f, trace_c = 0.f, fro2 = 0.f;
#pragma unroll
    for (int l = 0; l < 16; ++l) {
        float v = oar[l];
        if (l == k) trace_c = v; else rowsum += v;
        float c = ccr[l];
        fro2 += c * c;
    }
    float dd = sqrtf(rowsum) + 1e-12f;
    __shared__ float ddl[B_GR * K_CL];
    ddl[t] = dd;

    float dsv = dSb[t];
    float csv = csb[t];
    float ds2 = dsv * dsv, cs2 = csv * csv;
    float tr = trace_c;
#pragma unroll
    for (int msk = 8; msk >= 1; msk >>= 1) {
        tr   += __shfl_xor(tr,   msk, 16);
        ds2  += __shfl_xor(ds2,  msk, 16);
        cs2  += __shfl_xor(cs2,  msk, 16);
        fro2 += __shfl_xor(fro2, msk, 16);
    }
    float invfro = 1.0f / sqrtf(fro2);
    float osum = 0.f;
#pragma unroll
    for (int l = 0; l < 16; ++l) {
        float v = ccr[l] * invfro - ((l == k) ? 0.25f : 0.f);
        osum += v * v;
    }
#pragma unroll
    for (int msk = 8; msk >= 1; msk >>= 1) osum += __shfl_xor(osum, msk, 16);

    __shared__ float sp_s[B_GR], cl_s[B_GR], or_s[B_GR];
    if (k == 0) {
        float m2v = m2b[b];
        sp_s[b] = tr / m2v - ds2 / (m2v * m2v);
        cl_s[b] = sqrtf(cs2) / (float)npg * 4.0f - 1.0f;
        or_s[b] = sqrtf(osum);
    }
    __syncthreads();
    if (t == 0) {
        float a = 0.f, c = 0.f, o = 0.f;
        for (int i = 0; i < B_GR; ++i) { a += sp_s[i]; c += cl_s[i]; o += or_s[i]; }
        out[20480] = -a / 16.f;
        out[20481] = c / 16.f;
        out[20482] = o / 16.f;
    }

    // out_adj_norm -> out[16384 .. 20479]
#pragma unroll
    for (int l = 0; l < 16; ++l) {
        float v = (l == k) ? 0.f : oar[l] / (dd * ddl[b * 16 + l]);
        out[16384 + b * 256 + k * 16 + l] = v;
    }
}

// ---------------------------------------------------------------------------
extern "C" void kernel_launch(void* const* d_in, const int* in_sizes, int n_in,
                              void* d_out, int out_size, void* d_ws, size_t ws_size,
                              hipStream_t stream)
{
    const float* x    = (const float*)d_in[0];
    const float* W    = (const float*)d_in[1];
    const float* bvec = (const float*)d_in[2];
    const float* ew   = (const float*)d_in[3];
    const int* erow   = (const int*)d_in[4];
    const int* ecol   = (const int*)d_in[5];

    int Ntot = in_sizes[0] / F_DIM;           // 131072
    size_t E = (size_t)in_sizes[3];           // 4194304
    int npg  = Ntot / B_GR;                   // 8192
    int edges_per_graph = (int)(E / B_GR);    // 262144
    int nmask = Ntot - 1;                     // pow2 defensive mask

    char* ws = (char*)d_ws;
    size_t o = 0;
    float* ss   = (float*)(ws + o); o += (size_t)Ntot * 16 * 4;
    float* sraw = (float*)(ws + o); o += (size_t)Ntot * 16 * 4;
    size_t zoff = o;
    float* dvec = (float*)(ws + o); o += (size_t)Ntot * 4;
    float* outx = (float*)(ws + o); o += (size_t)B_GR * K_CL * F_DIM * 4;
    float* oadj = (float*)(ws + o); o += (size_t)B_GR * 256 * 4;
    float* CCb  = (float*)(ws + o); o += (size_t)B_GR * 256 * 4;
    float* dSb  = (float*)(ws + o); o += (size_t)B_GR * 16 * 4;
    float* csb  = (float*)(ws + o); o += (size_t)B_GR * 16 * 4;
    float* m2b  = (float*)(ws + o); o += (size_t)B_GR * 4;

    hipMemsetAsync(ws + zoff, 0, o - zoff, stream);

    k_assign<<<Ntot / 256, 256, 0, stream>>>(x, W, bvec, ss, sraw);

    int epg = 128;                                   // edges per 16-lane group
    int blocksE = (int)(E / (16 * (size_t)epg));     // 2048
    k_edge<<<blocksE, 256, 0, stream>>>(erow, ecol, ew, ss, oadj, dvec, epg, edges_per_graph, nmask);

    k_outx<<<Ntot / 256, 256, 0, stream>>>(x, sraw, outx, 64, npg);
    k_node<<<Ntot / 256, 256, 0, stream>>>(ss, dvec, CCb, dSb, csb, m2b, 64, npg);
    k_final<<<1, 256, 0, stream>>>(outx, oadj, CCb, dSb, csb, m2b, (float*)d_out, npg);
}

// Round 3
// 334.909 us; speedup vs baseline: 1.4189x; 1.4189x over previous
//
#include <hip/hip_runtime.h>
#include <math.h>

#define F_DIM 64
#define K_CL 16
#define B_GR 16

// ---------------------------------------------------------------------------
// K1: s = x@W + b ; ss = softmax(s). One thread per node. fp32 in/out.
// ---------------------------------------------------------------------------
__global__ __launch_bounds__(256) void k_assign(
    const float* __restrict__ x, const float* __restrict__ W, const float* __restrict__ bvec,
    float* __restrict__ ss, float* __restrict__ sraw)
{
    __shared__ float Wl[F_DIM * K_CL];
    __shared__ float bl[K_CL];
    int t = threadIdx.x;
    for (int idx = t; idx < F_DIM * K_CL; idx += 256) Wl[idx] = W[idx];
    if (t < K_CL) bl[t] = bvec[t];
    __syncthreads();

    size_t i = (size_t)blockIdx.x * 256 + t;
    float s[K_CL];
#pragma unroll
    for (int k = 0; k < 16; ++k) s[k] = bl[k];

    const float4* xp = reinterpret_cast<const float4*>(x + i * F_DIM);
#pragma unroll
    for (int j = 0; j < 16; ++j) {
        float4 q = xp[j];
        float xf[4] = {q.x, q.y, q.z, q.w};
#pragma unroll
        for (int ff = 0; ff < 4; ++ff) {
            int f = j * 4 + ff;
            float xv = xf[ff];
            const float4* wr = reinterpret_cast<const float4*>(&Wl[f * K_CL]);
            float4 w0 = wr[0], w1 = wr[1], w2 = wr[2], w3 = wr[3];
            s[0]  += xv * w0.x; s[1]  += xv * w0.y; s[2]  += xv * w0.z; s[3]  += xv * w0.w;
            s[4]  += xv * w1.x; s[5]  += xv * w1.y; s[6]  += xv * w1.z; s[7]  += xv * w1.w;
            s[8]  += xv * w2.x; s[9]  += xv * w2.y; s[10] += xv * w2.z; s[11] += xv * w2.w;
            s[12] += xv * w3.x; s[13] += xv * w3.y; s[14] += xv * w3.z; s[15] += xv * w3.w;
        }
    }

    float4* sp = reinterpret_cast<float4*>(sraw + i * K_CL);
    sp[0] = make_float4(s[0], s[1], s[2], s[3]);
    sp[1] = make_float4(s[4], s[5], s[6], s[7]);
    sp[2] = make_float4(s[8], s[9], s[10], s[11]);
    sp[3] = make_float4(s[12], s[13], s[14], s[15]);

    float m = s[0];
#pragma unroll
    for (int k = 1; k < 16; ++k) m = fmaxf(m, s[k]);
    float sum = 0.f;
#pragma unroll
    for (int k = 0; k < 16; ++k) { s[k] = __expf(s[k] - m); sum += s[k]; }
    float inv = 1.0f / sum;
    float4* qp = reinterpret_cast<float4*>(ss + i * K_CL);
    qp[0] = make_float4(s[0] * inv, s[1] * inv, s[2] * inv, s[3] * inv);
    qp[1] = make_float4(s[4] * inv, s[5] * inv, s[6] * inv, s[7] * inv);
    qp[2] = make_float4(s[8] * inv, s[9] * inv, s[10] * inv, s[11] * inv);
    qp[3] = make_float4(s[12] * inv, s[13] * inv, s[14] * inv, s[15] * inv);
}

// ---------------------------------------------------------------------------
// K2: oadj[b,k,l] += w * ss[row,k] * ss[col,l]  (per-edge rank-1).
// 16-lane groups, lane = k. XCD-affine swizzle: XCD (bid&7) handles graphs
// {xcd, xcd+8} only -> ss working set 1 MB per XCD L2. Edge data loaded
// coalesced in 16-edge batches, broadcast via shfl. No dvec (algebraic).
// ---------------------------------------------------------------------------
__global__ __launch_bounds__(256) void k_edge(
    const int* __restrict__ erow, const int* __restrict__ ecol, const float* __restrict__ ew,
    const float* __restrict__ ss, float* __restrict__ oadj,
    int epg, int edges_per_graph, int nmask)
{
    __shared__ float CCl[K_CL * K_CL];
    int t = threadIdx.x;
    CCl[t] = 0.f;
    __syncthreads();

    // swizzle: bid -> (graph, chunk); graph g lives on XCD g%8
    int bid = blockIdx.x;
    int xcd = bid & 7;
    int slot = bid >> 3;
    int graph = xcd + 8 * (slot & 1);
    int chunk = slot >> 1;

    int grp = t >> 4;
    int k = t & 15;
    size_t base = (size_t)graph * edges_per_graph
                + (size_t)chunk * (16 * epg)
                + (size_t)grp * epg;

    float acc[16];
#pragma unroll
    for (int l = 0; l < 16; ++l) acc[l] = 0.f;

    for (int j0 = 0; j0 < epg; j0 += 16) {
        size_t e0 = base + j0;
        int   rk = erow[e0 + k] & nmask;   // lane k holds edge e0+k
        int   ck = ecol[e0 + k] & nmask;
        float wk = ew[e0 + k];
#pragma unroll
        for (int j = 0; j < 16; ++j) {
            int r   = __shfl(rk, j, 16);
            int c   = __shfl(ck, j, 16);
            float w = __shfl(wk, j, 16);
            float a = ss[(size_t)r * 16 + k] * w;
            const float4* bp = reinterpret_cast<const float4*>(ss + (size_t)c * 16);
            float4 b0 = bp[0], b1 = bp[1], b2 = bp[2], b3 = bp[3];
            acc[0]  += a * b0.x; acc[1]  += a * b0.y; acc[2]  += a * b0.z; acc[3]  += a * b0.w;
            acc[4]  += a * b1.x; acc[5]  += a * b1.y; acc[6]  += a * b1.z; acc[7]  += a * b1.w;
            acc[8]  += a * b2.x; acc[9]  += a * b2.y; acc[10] += a * b2.z; acc[11] += a * b2.w;
            acc[12] += a * b3.x; acc[13] += a * b3.y; acc[14] += a * b3.z; acc[15] += a * b3.w;
        }
    }

    // intra-wave reduce across the 4 groups (same k), then LDS, then global
#pragma unroll
    for (int l = 0; l < 16; ++l) {
        acc[l] += __shfl_xor(acc[l], 16);
        acc[l] += __shfl_xor(acc[l], 32);
    }
    if ((t & 63) < 16) {
#pragma unroll
        for (int l = 0; l < 16; ++l) atomicAdd(&CCl[k * 16 + l], acc[l]);
    }
    __syncthreads();
    atomicAdd(oadj + graph * 256 + t, CCl[t]);
}

// ---------------------------------------------------------------------------
// K3: per-node pass (merged): outx[g,k,f] = sum_i sraw[i,k] x[i,f];
//     CC[g] = ss^T ss; cs[g,k] = sum_i ss[i,k].  One wave per node-slice,
//     lane = f for outx, lane = (g4,l) for CC. Block-level LDS reduction.
// ---------------------------------------------------------------------------
__global__ __launch_bounds__(256) void k_nodes(
    const float* __restrict__ x, const float* __restrict__ sraw, const float* __restrict__ ss,
    float* __restrict__ outx_acc, float* __restrict__ CCb, float* __restrict__ csb,
    int npw, int npg)
{
    __shared__ float redx[4 * K_CL * F_DIM];   // 16 KB
    __shared__ float CCl[256];
    __shared__ float csl[16];
    int t = threadIdx.x;
    CCl[t] = 0.f;
    if (t < 16) csl[t] = 0.f;
    __syncthreads();

    int wid = t >> 6, lane = t & 63;
    int g4 = lane >> 4, l = lane & 15;
    size_t base = ((size_t)blockIdx.x * 4 + wid) * npw;

    float accx[16];
#pragma unroll
    for (int k = 0; k < 16; ++k) accx[k] = 0.f;
    float accc[4] = {0.f, 0.f, 0.f, 0.f};
    float acccs = 0.f;

    for (int j = 0; j < npw; ++j) {
        size_t i = base + j;
        float xv = x[i * F_DIM + lane];
        const float4* sp = reinterpret_cast<const float4*>(sraw + i * K_CL);
        float4 s0 = sp[0], s1 = sp[1], s2 = sp[2], s3 = sp[3];
        accx[0]  += s0.x * xv; accx[1]  += s0.y * xv; accx[2]  += s0.z * xv; accx[3]  += s0.w * xv;
        accx[4]  += s1.x * xv; accx[5]  += s1.y * xv; accx[6]  += s1.z * xv; accx[7]  += s1.w * xv;
        accx[8]  += s2.x * xv; accx[9]  += s2.y * xv; accx[10] += s2.z * xv; accx[11] += s2.w * xv;
        accx[12] += s3.x * xv; accx[13] += s3.y * xv; accx[14] += s3.z * xv; accx[15] += s3.w * xv;

        float sv = ss[i * K_CL + l];
        accc[0] += __shfl(sv, g4 * 4 + 0, 16) * sv;
        accc[1] += __shfl(sv, g4 * 4 + 1, 16) * sv;
        accc[2] += __shfl(sv, g4 * 4 + 2, 16) * sv;
        accc[3] += __shfl(sv, g4 * 4 + 3, 16) * sv;
        acccs += sv;
    }

#pragma unroll
    for (int k = 0; k < 16; ++k) redx[wid * 1024 + k * 64 + lane] = accx[k];
#pragma unroll
    for (int j4 = 0; j4 < 4; ++j4)
        atomicAdd(&CCl[(g4 * 4 + j4) * 16 + l], accc[j4]);
    if (g4 == 0) atomicAdd(&csl[l], acccs);
    __syncthreads();

    int gb = (int)(((size_t)blockIdx.x * 4 * npw) / (size_t)npg);
    float* dst = outx_acc + gb * (K_CL * F_DIM);
    for (int idx = t; idx < K_CL * F_DIM; idx += 256) {
        float v = redx[idx] + redx[1024 + idx] + redx[2048 + idx] + redx[3072 + idx];
        atomicAdd(dst + idx, v);
    }
    atomicAdd(&CCb[gb * 256 + t], CCl[t]);
    if (t < 16) atomicAdd(&csb[gb * 16 + t], csl[t]);
}

// ---------------------------------------------------------------------------
// K5: finalize. dS = column sums of oadj, m2 = total sum (softmax rows sum
// to 1, so the degree vector is algebraically redundant).
// ---------------------------------------------------------------------------
__global__ __launch_bounds__(256) void k_final(
    const float* __restrict__ outx_acc, const float* __restrict__ oadj,
    const float* __restrict__ CCb, const float* __restrict__ csb,
    float* __restrict__ out, int npg)
{
    int t = threadIdx.x;

    for (int idx = t; idx < B_GR * K_CL * F_DIM; idx += 256) {
        float v = outx_acc[idx];
        float r = (v > 0.f) ? (1.0507009873554805f * v)
                            : (1.0507009873554805f * 1.6732632423543772f * (__expf(v) - 1.0f));
        out[idx] = r;
    }

    int b = t >> 4, k = t & 15;
    const float* oar = oadj + b * 256 + k * 16;
    const float* ccr = CCb + b * 256 + k * 16;

    float rowsum_off = 0.f, trace_c = 0.f, rowsum_all = 0.f, fro2 = 0.f, colsum = 0.f;
#pragma unroll
    for (int l = 0; l < 16; ++l) {
        float v = oar[l];
        rowsum_all += v;
        if (l == k) trace_c = v; else rowsum_off += v;
        float c = ccr[l];
        fro2 += c * c;
        colsum += oadj[b * 256 + l * 16 + k];   // column k of block b
    }
    float dd = sqrtf(rowsum_off) + 1e-12f;
    __shared__ float ddl[B_GR * K_CL];
    ddl[t] = dd;

    float csv = csb[t];
    float ds2 = colsum * colsum, cs2 = csv * csv;
    float tr = trace_c, m2 = rowsum_all;
#pragma unroll
    for (int msk = 8; msk >= 1; msk >>= 1) {
        tr   += __shfl_xor(tr,   msk, 16);
        ds2  += __shfl_xor(ds2,  msk, 16);
        cs2  += __shfl_xor(cs2,  msk, 16);
        fro2 += __shfl_xor(fro2, msk, 16);
        m2   += __shfl_xor(m2,   msk, 16);
    }
    float invfro = 1.0f / sqrtf(fro2);
    float osum = 0.f;
#pragma unroll
    for (int l = 0; l < 16; ++l) {
        float v = ccr[l] * invfro - ((l == k) ? 0.25f : 0.f);
        osum += v * v;
    }
#pragma unroll
    for (int msk = 8; msk >= 1; msk >>= 1) osum += __shfl_xor(osum, msk, 16);

    __shared__ float sp_s[B_GR], cl_s[B_GR], or_s[B_GR];
    if (k == 0) {
        sp_s[b] = tr / m2 - ds2 / (m2 * m2);
        cl_s[b] = sqrtf(cs2) / (float)npg * 4.0f - 1.0f;
        or_s[b] = sqrtf(osum);
    }
    __syncthreads();
    if (t == 0) {
        float a = 0.f, c = 0.f, o = 0.f;
        for (int i = 0; i < B_GR; ++i) { a += sp_s[i]; c += cl_s[i]; o += or_s[i]; }
        out[20480] = -a / 16.f;
        out[20481] = c / 16.f;
        out[20482] = o / 16.f;
    }

#pragma unroll
    for (int l = 0; l < 16; ++l) {
        float v = (l == k) ? 0.f : oar[l] / (dd * ddl[b * 16 + l]);
        out[16384 + b * 256 + k * 16 + l] = v;
    }
}

// ---------------------------------------------------------------------------
extern "C" void kernel_launch(void* const* d_in, const int* in_sizes, int n_in,
                              void* d_out, int out_size, void* d_ws, size_t ws_size,
                              hipStream_t stream)
{
    const float* x    = (const float*)d_in[0];
    const float* W    = (const float*)d_in[1];
    const float* bvec = (const float*)d_in[2];
    const float* ew   = (const float*)d_in[3];
    const int* erow   = (const int*)d_in[4];
    const int* ecol   = (const int*)d_in[5];

    int Ntot = in_sizes[0] / F_DIM;           // 131072
    size_t E = (size_t)in_sizes[3];           // 4194304
    int npg  = Ntot / B_GR;                   // 8192
    int edges_per_graph = (int)(E / B_GR);    // 262144
    int nmask = Ntot - 1;

    char* ws = (char*)d_ws;
    size_t o = 0;
    float* ss   = (float*)(ws + o); o += (size_t)Ntot * 16 * 4;
    float* sraw = (float*)(ws + o); o += (size_t)Ntot * 16 * 4;
    size_t zoff = o;
    float* outx = (float*)(ws + o); o += (size_t)B_GR * K_CL * F_DIM * 4;
    float* oadj = (float*)(ws + o); o += (size_t)B_GR * 256 * 4;
    float* CCb  = (float*)(ws + o); o += (size_t)B_GR * 256 * 4;
    float* csb  = (float*)(ws + o); o += (size_t)B_GR * 16 * 4;

    hipMemsetAsync(ws + zoff, 0, o - zoff, stream);

    k_assign<<<Ntot / 256, 256, 0, stream>>>(x, W, bvec, ss, sraw);

    int epg = 128;                                   // edges per 16-lane group
    int blocksE = (int)(E / (16 * (size_t)epg));     // 2048
    k_edge<<<blocksE, 256, 0, stream>>>(erow, ecol, ew, ss, oadj, epg, edges_per_graph, nmask);

    k_nodes<<<Ntot / 256, 256, 0, stream>>>(x, sraw, ss, outx, CCb, csb, 64, npg);
    k_final<<<1, 256, 0, stream>>>(outx, oadj, CCb, csb, (float*)d_out, npg);
}

// Round 4
// 295.809 us; speedup vs baseline: 1.6065x; 1.1322x over previous
//
#include <hip/hip_runtime.h>
#include <math.h>

#define F_DIM 64
#define K_CL 16
#define B_GR 16

// ---------------------------------------------------------------------------
// K1: s = x@W + b ; ss = softmax(s). One thread per node. fp32 in/out.
// ---------------------------------------------------------------------------
__global__ __launch_bounds__(256) void k_assign(
    const float* __restrict__ x, const float* __restrict__ W, const float* __restrict__ bvec,
    float* __restrict__ ss, float* __restrict__ sraw)
{
    __shared__ float Wl[F_DIM * K_CL];
    __shared__ float bl[K_CL];
    int t = threadIdx.x;
    for (int idx = t; idx < F_DIM * K_CL; idx += 256) Wl[idx] = W[idx];
    if (t < K_CL) bl[t] = bvec[t];
    __syncthreads();

    size_t i = (size_t)blockIdx.x * 256 + t;
    float s[K_CL];
#pragma unroll
    for (int k = 0; k < 16; ++k) s[k] = bl[k];

    const float4* xp = reinterpret_cast<const float4*>(x + i * F_DIM);
#pragma unroll
    for (int j = 0; j < 16; ++j) {
        float4 q = xp[j];
        float xf[4] = {q.x, q.y, q.z, q.w};
#pragma unroll
        for (int ff = 0; ff < 4; ++ff) {
            int f = j * 4 + ff;
            float xv = xf[ff];
            const float4* wr = reinterpret_cast<const float4*>(&Wl[f * K_CL]);
            float4 w0 = wr[0], w1 = wr[1], w2 = wr[2], w3 = wr[3];
            s[0]  += xv * w0.x; s[1]  += xv * w0.y; s[2]  += xv * w0.z; s[3]  += xv * w0.w;
            s[4]  += xv * w1.x; s[5]  += xv * w1.y; s[6]  += xv * w1.z; s[7]  += xv * w1.w;
            s[8]  += xv * w2.x; s[9]  += xv * w2.y; s[10] += xv * w2.z; s[11] += xv * w2.w;
            s[12] += xv * w3.x; s[13] += xv * w3.y; s[14] += xv * w3.z; s[15] += xv * w3.w;
        }
    }

    float4* sp = reinterpret_cast<float4*>(sraw + i * K_CL);
    sp[0] = make_float4(s[0], s[1], s[2], s[3]);
    sp[1] = make_float4(s[4], s[5], s[6], s[7]);
    sp[2] = make_float4(s[8], s[9], s[10], s[11]);
    sp[3] = make_float4(s[12], s[13], s[14], s[15]);

    float m = s[0];
#pragma unroll
    for (int k = 1; k < 16; ++k) m = fmaxf(m, s[k]);
    float sum = 0.f;
#pragma unroll
    for (int k = 0; k < 16; ++k) { s[k] = __expf(s[k] - m); sum += s[k]; }
    float inv = 1.0f / sum;
    float4* qp = reinterpret_cast<float4*>(ss + i * K_CL);
    qp[0] = make_float4(s[0] * inv, s[1] * inv, s[2] * inv, s[3] * inv);
    qp[1] = make_float4(s[4] * inv, s[5] * inv, s[6] * inv, s[7] * inv);
    qp[2] = make_float4(s[8] * inv, s[9] * inv, s[10] * inv, s[11] * inv);
    qp[3] = make_float4(s[12] * inv, s[13] * inv, s[14] * inv, s[15] * inv);
}

// ---------------------------------------------------------------------------
// K2: oadj partials. Lane m=(j,q): j=edge-of-16, q=l-quad. Per 16-edge batch:
// 1 coalesced b-row load (dwordx4, zero redundancy), 4 a-row loads, w folded
// into b, 64-reg accumulator acc[k][qq] covering cells (k, q*4+qq).
// XCD-affine graph swizzle. Non-atomic per-block partial store.
// ---------------------------------------------------------------------------
__global__ __launch_bounds__(256, 4) void k_edge(
    const int* __restrict__ erow, const int* __restrict__ ecol, const float* __restrict__ ew,
    const float* __restrict__ ss, float* __restrict__ padj,
    int edges_per_block, int edges_per_graph, int nmask)
{
    __shared__ float CCl[256];
    int t = threadIdx.x;
    CCl[t] = 0.f;
    __syncthreads();

    int bid = blockIdx.x;
    int xcd = bid & 7;
    int slot = bid >> 3;
    int graph = xcd + 8 * (slot & 1);
    int chunk = slot >> 1;                    // 0..63

    int wid = t >> 6;
    int lane = t & 63;
    int q = lane & 3;
    int jsel = lane >> 2;                     // 0..15

    int epw = edges_per_block >> 2;           // edges per wave
    size_t base = (size_t)graph * edges_per_graph
                + (size_t)chunk * edges_per_block
                + (size_t)wid * epw;

    float acc[64];
#pragma unroll
    for (int i = 0; i < 64; ++i) acc[i] = 0.f;

    for (int e0 = 0; e0 < epw; e0 += 64) {
        size_t eb = base + e0 + lane;
        int rv = erow[eb] & nmask;
        int cv = ecol[eb] & nmask;
        float wv = ew[eb];
#pragma unroll
        for (int sb = 0; sb < 4; ++sb) {
            int src = sb * 16 + jsel;
            int r   = __shfl(rv, src, 64);
            int c   = __shfl(cv, src, 64);
            float w = __shfl(wv, src, 64);

            const float4* bp = reinterpret_cast<const float4*>(ss + (size_t)c * 16);
            float4 b = bp[q];
            b.x *= w; b.y *= w; b.z *= w; b.w *= w;

            const float4* ap = reinterpret_cast<const float4*>(ss + (size_t)r * 16);
            float4 a0 = ap[0], a1 = ap[1], a2 = ap[2], a3 = ap[3];
            float a[16] = {a0.x, a0.y, a0.z, a0.w, a1.x, a1.y, a1.z, a1.w,
                           a2.x, a2.y, a2.z, a2.w, a3.x, a3.y, a3.z, a3.w};
#pragma unroll
            for (int k = 0; k < 16; ++k) {
                acc[k * 4 + 0] += a[k] * b.x;
                acc[k * 4 + 1] += a[k] * b.y;
                acc[k * 4 + 2] += a[k] * b.z;
                acc[k * 4 + 3] += a[k] * b.w;
            }
        }
    }

    // reduce across the 16 lanes sharing q (xor masks 4,8,16,32 = all of j)
#pragma unroll
    for (int i = 0; i < 64; ++i) {
        acc[i] += __shfl_xor(acc[i], 4);
        acc[i] += __shfl_xor(acc[i], 8);
        acc[i] += __shfl_xor(acc[i], 16);
        acc[i] += __shfl_xor(acc[i], 32);
    }
    if (lane < 4) {  // lane == q class representative
#pragma unroll
        for (int k = 0; k < 16; ++k)
#pragma unroll
            for (int qq = 0; qq < 4; ++qq)
                atomicAdd(&CCl[k * 16 + lane * 4 + qq], acc[k * 4 + qq]);
    }
    __syncthreads();
    padj[(size_t)bid * 256 + t] = CCl[t];
}

// ---------------------------------------------------------------------------
// K3: per-node pass: outx[g,k,f], CC[g]=ss^T ss, cs[g,k]. Partial stores.
// ---------------------------------------------------------------------------
__global__ __launch_bounds__(256) void k_nodes(
    const float* __restrict__ x, const float* __restrict__ sraw, const float* __restrict__ ss,
    float* __restrict__ poutx, float* __restrict__ pCC, float* __restrict__ pcs,
    int npw)
{
    __shared__ float redx[4 * K_CL * F_DIM];   // 16 KB
    __shared__ float CCl[256];
    __shared__ float csl[16];
    int t = threadIdx.x;
    CCl[t] = 0.f;
    if (t < 16) csl[t] = 0.f;
    __syncthreads();

    int wid = t >> 6, lane = t & 63;
    int g4 = lane >> 4, l = lane & 15;
    size_t base = ((size_t)blockIdx.x * 4 + wid) * npw;

    float accx[16];
#pragma unroll
    for (int k = 0; k < 16; ++k) accx[k] = 0.f;
    float accc[4] = {0.f, 0.f, 0.f, 0.f};
    float acccs = 0.f;

    for (int j = 0; j < npw; ++j) {
        size_t i = base + j;
        float xv = x[i * F_DIM + lane];
        const float4* sp = reinterpret_cast<const float4*>(sraw + i * K_CL);
        float4 s0 = sp[0], s1 = sp[1], s2 = sp[2], s3 = sp[3];
        accx[0]  += s0.x * xv; accx[1]  += s0.y * xv; accx[2]  += s0.z * xv; accx[3]  += s0.w * xv;
        accx[4]  += s1.x * xv; accx[5]  += s1.y * xv; accx[6]  += s1.z * xv; accx[7]  += s1.w * xv;
        accx[8]  += s2.x * xv; accx[9]  += s2.y * xv; accx[10] += s2.z * xv; accx[11] += s2.w * xv;
        accx[12] += s3.x * xv; accx[13] += s3.y * xv; accx[14] += s3.z * xv; accx[15] += s3.w * xv;

        float sv = ss[i * K_CL + l];
        accc[0] += __shfl(sv, g4 * 4 + 0, 16) * sv;
        accc[1] += __shfl(sv, g4 * 4 + 1, 16) * sv;
        accc[2] += __shfl(sv, g4 * 4 + 2, 16) * sv;
        accc[3] += __shfl(sv, g4 * 4 + 3, 16) * sv;
        acccs += sv;
    }

#pragma unroll
    for (int k = 0; k < 16; ++k) redx[wid * 1024 + k * 64 + lane] = accx[k];
#pragma unroll
    for (int j4 = 0; j4 < 4; ++j4)
        atomicAdd(&CCl[(g4 * 4 + j4) * 16 + l], accc[j4]);
    if (g4 == 0) atomicAdd(&csl[l], acccs);
    __syncthreads();

    int bid = blockIdx.x;
    for (int idx = t; idx < K_CL * F_DIM; idx += 256) {
        float v = redx[idx] + redx[1024 + idx] + redx[2048 + idx] + redx[3072 + idx];
        poutx[(size_t)bid * 1024 + idx] = v;
    }
    pCC[(size_t)bid * 256 + t] = CCl[t];
    if (t < 16) pcs[(size_t)bid * 16 + t] = csl[t];
}

// ---------------------------------------------------------------------------
// K4: reduce partials (one block per graph) + fused selu epilogue for out_x.
// ---------------------------------------------------------------------------
__global__ __launch_bounds__(256) void k_reduce(
    const float* __restrict__ padj, const float* __restrict__ poutx,
    const float* __restrict__ pCC, const float* __restrict__ pcs,
    float* __restrict__ oadj, float* __restrict__ CCb, float* __restrict__ csb,
    float* __restrict__ out, int adj_slots, int node_slots)
{
    int g = blockIdx.x, t = threadIdx.x;

    float s = 0.f;
    for (int i = 0; i < adj_slots; ++i)
        s += padj[((size_t)g * adj_slots + i) * 256 + t];
    oadj[g * 256 + t] = s;

    float c = 0.f;
    for (int i = 0; i < node_slots; ++i)
        c += pCC[((size_t)g * node_slots + i) * 256 + t];
    CCb[g * 256 + t] = c;

    if (t < 16) {
        float cs = 0.f;
        for (int i = 0; i < node_slots; ++i)
            cs += pcs[((size_t)g * node_slots + i) * 16 + t];
        csb[g * 16 + t] = cs;
    }

    for (int idx = t; idx < K_CL * F_DIM; idx += 256) {
        float v = 0.f;
        for (int i = 0; i < node_slots; ++i)
            v += poutx[((size_t)g * node_slots + i) * 1024 + idx];
        float r = (v > 0.f) ? (1.0507009873554805f * v)
                            : (1.0507009873554805f * 1.6732632423543772f * (__expf(v) - 1.0f));
        out[g * 1024 + idx] = r;
    }
}

// ---------------------------------------------------------------------------
// K5: finalize losses + out_adj_norm. dS = column sums of oadj, m2 = total
// sum (softmax rows sum to 1 -> degree vector algebraically redundant).
// ---------------------------------------------------------------------------
__global__ __launch_bounds__(256) void k_final(
    const float* __restrict__ oadj, const float* __restrict__ CCb,
    const float* __restrict__ csb, float* __restrict__ out, int npg)
{
    int t = threadIdx.x;
    int b = t >> 4, k = t & 15;
    const float* oar = oadj + b * 256 + k * 16;
    const float* ccr = CCb + b * 256 + k * 16;

    float rowsum_off = 0.f, trace_c = 0.f, rowsum_all = 0.f, fro2 = 0.f, colsum = 0.f;
#pragma unroll
    for (int l = 0; l < 16; ++l) {
        float v = oar[l];
        rowsum_all += v;
        if (l == k) trace_c = v; else rowsum_off += v;
        float c = ccr[l];
        fro2 += c * c;
        colsum += oadj[b * 256 + l * 16 + k];
    }
    float dd = sqrtf(rowsum_off) + 1e-12f;
    __shared__ float ddl[B_GR * K_CL];
    ddl[t] = dd;

    float csv = csb[t];
    float ds2 = colsum * colsum, cs2 = csv * csv;
    float tr = trace_c, m2 = rowsum_all;
#pragma unroll
    for (int msk = 8; msk >= 1; msk >>= 1) {
        tr   += __shfl_xor(tr,   msk, 16);
        ds2  += __shfl_xor(ds2,  msk, 16);
        cs2  += __shfl_xor(cs2,  msk, 16);
        fro2 += __shfl_xor(fro2, msk, 16);
        m2   += __shfl_xor(m2,   msk, 16);
    }
    float invfro = 1.0f / sqrtf(fro2);
    float osum = 0.f;
#pragma unroll
    for (int l = 0; l < 16; ++l) {
        float v = ccr[l] * invfro - ((l == k) ? 0.25f : 0.f);
        osum += v * v;
    }
#pragma unroll
    for (int msk = 8; msk >= 1; msk >>= 1) osum += __shfl_xor(osum, msk, 16);

    __shared__ float sp_s[B_GR], cl_s[B_GR], or_s[B_GR];
    if (k == 0) {
        sp_s[b] = tr / m2 - ds2 / (m2 * m2);
        cl_s[b] = sqrtf(cs2) / (float)npg * 4.0f - 1.0f;
        or_s[b] = sqrtf(osum);
    }
    __syncthreads();
    if (t == 0) {
        float a = 0.f, c = 0.f, o = 0.f;
        for (int i = 0; i < B_GR; ++i) { a += sp_s[i]; c += cl_s[i]; o += or_s[i]; }
        out[20480] = -a / 16.f;
        out[20481] = c / 16.f;
        out[20482] = o / 16.f;
    }

#pragma unroll
    for (int l = 0; l < 16; ++l) {
        float v = (l == k) ? 0.f : oar[l] / (dd * ddl[b * 16 + l]);
        out[16384 + b * 256 + k * 16 + l] = v;
    }
}

// ---------------------------------------------------------------------------
extern "C" void kernel_launch(void* const* d_in, const int* in_sizes, int n_in,
                              void* d_out, int out_size, void* d_ws, size_t ws_size,
                              hipStream_t stream)
{
    const float* x    = (const float*)d_in[0];
    const float* W    = (const float*)d_in[1];
    const float* bvec = (const float*)d_in[2];
    const float* ew   = (const float*)d_in[3];
    const int* erow   = (const int*)d_in[4];
    const int* ecol   = (const int*)d_in[5];

    int Ntot = in_sizes[0] / F_DIM;           // 131072
    size_t E = (size_t)in_sizes[3];           // 4194304
    int npg  = Ntot / B_GR;                   // 8192
    int edges_per_graph = (int)(E / B_GR);    // 262144
    int nmask = Ntot - 1;

    const int ADJ_BLOCKS  = 1024;             // 64 per graph
    const int NODE_BLOCKS = 256;              // 16 per graph
    int adj_slots  = ADJ_BLOCKS / B_GR;       // 64
    int node_slots = NODE_BLOCKS / B_GR;      // 16
    int edges_per_block = (int)(E / ADJ_BLOCKS);          // 4096
    int npw = Ntot / (NODE_BLOCKS * 4);                   // 128

    char* ws = (char*)d_ws;
    size_t o = 0;
    float* ss    = (float*)(ws + o); o += (size_t)Ntot * 16 * 4;
    float* sraw  = (float*)(ws + o); o += (size_t)Ntot * 16 * 4;
    float* padj  = (float*)(ws + o); o += (size_t)ADJ_BLOCKS * 256 * 4;
    float* poutx = (float*)(ws + o); o += (size_t)NODE_BLOCKS * 1024 * 4;
    float* pCC   = (float*)(ws + o); o += (size_t)NODE_BLOCKS * 256 * 4;
    float* pcs   = (float*)(ws + o); o += (size_t)NODE_BLOCKS * 16 * 4;
    float* oadj  = (float*)(ws + o); o += (size_t)B_GR * 256 * 4;
    float* CCb   = (float*)(ws + o); o += (size_t)B_GR * 256 * 4;
    float* csb   = (float*)(ws + o); o += (size_t)B_GR * 16 * 4;

    k_assign<<<Ntot / 256, 256, 0, stream>>>(x, W, bvec, ss, sraw);
    k_edge<<<ADJ_BLOCKS, 256, 0, stream>>>(erow, ecol, ew, ss, padj,
                                           edges_per_block, edges_per_graph, nmask);
    k_nodes<<<NODE_BLOCKS, 256, 0, stream>>>(x, sraw, ss, poutx, pCC, pcs, npw);
    k_reduce<<<B_GR, 256, 0, stream>>>(padj, poutx, pCC, pcs, oadj, CCb, csb,
                                       (float*)d_out, adj_slots, node_slots);
    k_final<<<1, 256, 0, stream>>>(oadj, CCb, csb, (float*)d_out, npg);
}